// Round 5
// baseline (2456.140 us; speedup 1.0000x reference)
//
#include <hip/hip_runtime.h>

// LSTM: x[64][512][512] fp32, U[512][4096], W[1024][4096], bias[4096]
// out = hidden_seq[64][512][1024] fp32 ++ h_T[64][1024] ++ c_T[64][1024]
//
// Phase A (parallel): cast x->f16; pack W,U into per-lane MFMA B-fragment order.
// Phase B (persistent): R7 = R3's proven handshake, sync domain halved.
//  512-thread WGs (8 waves), 32 WGs per batch-group, 128 WGs total.
//  - wave wq in 0..7: gate q = wq&3, column-half cz = wq>>2; WG covers 32 h-cols.
//  - per-wave code (weights in regs, 16 x@U + 32 h@W MFMAs, poll, publish+flag)
//    is byte-isomorphic to R3; only the decomposition changes.
//  - WHY: R6 falsified LLC poll contention (poll waves /4 -> FETCH & dur
//    unchanged). Remaining unexplained ~5000 cy/step is per-step resync skew
//    (max over 64 producer WGs of jittery LLC RTs). N=32 halves that domain
//    and halves the h-load burst. Half the CUs idle: fine, chain is latency-
//    bound, not throughput-bound.
//  - 16KB dynamic LDS pad at launch forces 1 WG/CU (2x74.5KB would fit in
//    160KB otherwise and a doubled-up CU would add skew).

typedef _Float16 f16x8 __attribute__((ext_vector_type(8)));
typedef float f32x4 __attribute__((ext_vector_type(4)));

__device__ __forceinline__ unsigned short f2h_bits(float f) {
  union { _Float16 h; unsigned short u; } cv;
  cv.h = (_Float16)f;
  return cv.u;
}
__device__ __forceinline__ unsigned int aload(unsigned int* p) {
  return __hip_atomic_load(p, __ATOMIC_RELAXED, __HIP_MEMORY_SCOPE_AGENT);
}
__device__ __forceinline__ void astore(unsigned int* p, unsigned int v) {
  __hip_atomic_store(p, v, __ATOMIC_RELAXED, __HIP_MEMORY_SCOPE_AGENT);
}
__device__ __forceinline__ unsigned long long aload64(unsigned long long* p) {
  return __hip_atomic_load(p, __ATOMIC_RELAXED, __HIP_MEMORY_SCOPE_AGENT);
}

// ---- Phase A kernels ------------------------------------------------------

__global__ void cast_x_kernel(const float* __restrict__ x, unsigned short* __restrict__ xh) {
  int i = blockIdx.x * 256 + threadIdx.x;            // [0, 4194304)
  float4 v = ((const float4*)x)[i];
  ushort4 o;
  o.x = f2h_bits(v.x); o.y = f2h_bits(v.y);
  o.z = f2h_bits(v.z); o.w = f2h_bits(v.w);
  ((ushort4*)xh)[i] = o;
}

// Wp[((T*32+kt)*64+l)*8 + j] = f16(W[kt*32 + (l>>4)*8 + j][(T>>6)*1024 + (T&63)*16 + (l&15)])
__global__ void pack_W_kernel(const float* __restrict__ W, unsigned short* __restrict__ Wp) {
  int idx = blockIdx.x * 256 + threadIdx.x;          // [0, 524288)
  int l  = idx & 63;
  int kt = (idx >> 6) & 31;
  int T  = idx >> 11;                                // 0..255
  int q = T >> 6, jt = T & 63;
  int g  = q * 1024 + jt * 16 + (l & 15);
  int kb = kt * 32 + ((l >> 4) << 3);
  unsigned short tmp[8];
#pragma unroll
  for (int j = 0; j < 8; ++j) tmp[j] = f2h_bits(W[(size_t)(kb + j) * 4096 + g]);
  ((uint4*)Wp)[idx] = *(const uint4*)tmp;
}

__global__ void pack_U_kernel(const float* __restrict__ U, unsigned short* __restrict__ Up) {
  int idx = blockIdx.x * 256 + threadIdx.x;          // [0, 262144)
  int l  = idx & 63;
  int kt = (idx >> 6) & 15;
  int T  = idx >> 10;                                // 0..255
  int q = T >> 6, jt = T & 63;
  int g  = q * 1024 + jt * 16 + (l & 15);
  int kb = kt * 32 + ((l >> 4) << 3);
  unsigned short tmp[8];
#pragma unroll
  for (int j = 0; j < 8; ++j) tmp[j] = f2h_bits(U[(size_t)(kb + j) * 4096 + g]);
  ((uint4*)Up)[idx] = *(const uint4*)tmp;
}

// ---- Phase B: persistent recurrent kernel ---------------------------------

#define OUT_HS 33554432   // 64*512*1024

__global__ __launch_bounds__(512, 1) void lstm_rec_kernel(
    const unsigned short* __restrict__ xh,   // [64][512][512] f16
    const unsigned short* __restrict__ Wp,   // packed f16
    const unsigned short* __restrict__ Up,   // packed f16
    const float* __restrict__ bias,          // [4096]
    float* __restrict__ out,
    unsigned int* hb,                        // [4 grp][2 slot][16][1024] f16 (uint pairs)
    unsigned int* flags)                     // [4 grp][32 wg][8 wave]
{
  __shared__ unsigned short lx[2][16 * 520]; // x tiles, rows padded +8, double-buffered
  __shared__ unsigned short lh[16 * 1032];   // h tile, rows padded +8
  __shared__ float gl[8][16][16];            // gate exchange (8 waves)

  const int tid  = threadIdx.x;              // 0..511
  const int lane = tid & 63;
  const int wq   = tid >> 6;                 // 0..7
  const int q    = wq & 3;                   // gate section (i,f,g,o)
  const int cz   = wq >> 2;                  // column half within WG tile
  const int m    = lane & 15;
  const int quad = lane >> 4;

  const int bx  = blockIdx.x;                // 0..127
  const int x8  = bx & 7;
  const int grp = x8 >> 1;                            // 0..3 batch group
  const int jt2 = ((bx >> 3) << 1) | (x8 & 1);        // 0..31 32-col tile
  const int b0  = grp * 16;
  const int T   = q * 64 + jt2 * 2 + cz;              // packed 16-col tile id

  // Register/AGPR-resident weight fragments (per-wave identical to R3)
  f16x8 wf[32];
  {
    const f16x8* src = (const f16x8*)Wp + (size_t)T * 2048 + lane;
#pragma unroll
    for (int kt = 0; kt < 32; ++kt) wf[kt] = src[kt * 64];
  }
  f16x8 uf[16];
  {
    const f16x8* src = (const f16x8*)Up + (size_t)T * 1024 + lane;
#pragma unroll
    for (int k2 = 0; k2 < 16; ++k2) uf[k2] = src[k2 * 64];
  }
  const float bias_v = bias[q * 1024 + (jt2 * 2 + cz) * 16 + m];

  const int eb = tid >> 5, ej = tid & 31;    // epilogue: batch row / column(0..31)
  const int b_out = b0 + eb;
  const int j_out = jt2 * 32 + ej;
  float c = 0.f;

  unsigned int* my_flag   = flags + grp * 256 + jt2 * 8 + wq;
  unsigned int* grp_flags = flags + grp * 256;

  const uint2* xsrc = (const uint2*)xh;

  // Prologue: stage x(0) into lx[0]  (512 thr x 4 iters x 8B = 16KB)
  uint2 xr[4];
#pragma unroll
  for (int i = 0; i < 4; ++i) {
    int idx = tid + i * 512, row = idx >> 7, off = idx & 127;
    xr[i] = xsrc[(size_t)((b0 + row) * 512 + 0) * 128 + off];
  }
#pragma unroll
  for (int i = 0; i < 4; ++i) {
    int idx = tid + i * 512, row = idx >> 7, off = idx & 127;
    *(uint2*)&lx[0][row * 520 + off * 4] = xr[i];
  }

  for (int t = 0; t < 512; ++t) {
    __syncthreads();                         // S1: lx[t&1] ready; gl(t-1) reads done

    // Prefetch x(t+1) into regs — shadowed by the flag poll + h load below.
    if (t < 511) {
#pragma unroll
      for (int i = 0; i < 4; ++i) {
        int idx = tid + i * 512, row = idx >> 7, off = idx & 127;
        xr[i] = xsrc[(size_t)((b0 + row) * 512 + (t + 1)) * 128 + off];
      }
    }

    f32x4 a0 = {bias_v, bias_v, bias_v, bias_v};
    f32x4 a1 = {0.f, 0.f, 0.f, 0.f};

    const unsigned short* lxt = lx[t & 1];
#pragma unroll
    for (int k2 = 0; k2 < 16; ++k2) {
      f16x8 xa = *(const f16x8*)&lxt[m * 520 + k2 * 32 + quad * 8];
      if (k2 & 1) a1 = __builtin_amdgcn_mfma_f32_16x16x32_f16(xa, uf[k2], a1, 0, 0, 0);
      else        a0 = __builtin_amdgcn_mfma_f32_16x16x32_f16(xa, uf[k2], a0, 0, 0, 0);
    }

    if (t > 0) {
      // All 8 waves poll all 256 per-wave flags of the group (R3 semantics).
      unsigned int* f = grp_flags + lane;
      while (true) {
        unsigned int v0 = aload(f);
        unsigned int v1 = aload(f + 64);
        unsigned int v2 = aload(f + 128);
        unsigned int v3 = aload(f + 192);
        unsigned int mn = v0 < v1 ? v0 : v1;
        unsigned int mn2 = v2 < v3 ? v2 : v3;
        mn = mn < mn2 ? mn : mn2;
        if (!__any((int)(mn < (unsigned int)t))) break;
        __builtin_amdgcn_s_sleep(1);
      }

      // Stage h(t-1) -> regs -> LDS (coherent loads; 512 thr x 8 iters x 8B)
      unsigned long long* src = (unsigned long long*)hb +
          (size_t)(grp * 2 + ((t - 1) & 1)) * 4096;
      unsigned long long u[8];
#pragma unroll
      for (int i = 0; i < 8; ++i) u[i] = aload64(src + tid + i * 512);
#pragma unroll
      for (int i = 0; i < 8; ++i) {
        int idx = tid + i * 512, row = idx >> 8, off = idx & 255;
        *(unsigned long long*)&lh[row * 1032 + off * 4] = u[i];
      }
      __syncthreads();                       // B2: lh ready

#pragma unroll
      for (int kt = 0; kt < 32; ++kt) {
        f16x8 ha = *(const f16x8*)&lh[m * 1032 + kt * 32 + quad * 8];
        if (kt & 1) a1 = __builtin_amdgcn_mfma_f32_16x16x32_f16(ha, wf[kt], a1, 0, 0, 0);
        else        a0 = __builtin_amdgcn_mfma_f32_16x16x32_f16(ha, wf[kt], a0, 0, 0, 0);
      }
    }

    // Write next x tile into the other LDS buffer (loads long since complete).
    if (t < 511) {
#pragma unroll
      for (int i = 0; i < 4; ++i) {
        int idx = tid + i * 512, row = idx >> 7, off = idx & 127;
        *(uint2*)&lx[(t + 1) & 1][row * 520 + off * 4] = xr[i];
      }
    }

    // C/D layout: col = lane&15, row = quad*4 + r
#pragma unroll
    for (int r = 0; r < 4; ++r) gl[wq][quad * 4 + r][m] = a0[r] + a1[r];
    __syncthreads();                         // S3: gates ready

    const int hs = ej >> 4, jl = ej & 15;    // column half / col within 16
    float iv = gl[hs * 4 + 0][eb][jl], fvv = gl[hs * 4 + 1][eb][jl];
    float gv = gl[hs * 4 + 2][eb][jl], ov  = gl[hs * 4 + 3][eb][jl];
    float ig = 1.f / (1.f + __expf(-iv));
    float fg = 1.f / (1.f + __expf(-fvv));
    float og = 1.f / (1.f + __expf(-ov));
    float e2g = __expf(2.f * gv);
    float gg = 1.f - 2.f / (e2g + 1.f);      // tanh, inf-safe
    c = fg * c + ig * gg;
    float e2c = __expf(2.f * c);
    float tc = 1.f - 2.f / (e2c + 1.f);
    float h = og * tc;

    out[(size_t)b_out * (512 * 1024) + (size_t)t * 1024 + j_out] = h;
    if (t == 511) {
      out[OUT_HS + b_out * 1024 + j_out] = h;
      out[OUT_HS + 65536 + b_out * 1024 + j_out] = c;
    } else {
      // Publish h(t): pack 2 f16 per uint (even ej stores both halves).
      unsigned int hbits = (unsigned int)f2h_bits(h);
      unsigned int nbits = (unsigned int)__shfl_down((int)hbits, 1);
      if ((ej & 1) == 0) {
        unsigned int* dst = hb + (size_t)(grp * 2 + (t & 1)) * 8192 +
                            eb * 512 + jt2 * 16 + (ej >> 1);
        astore(dst, hbits | (nbits << 16));
      }
      asm volatile("s_waitcnt vmcnt(0)" ::: "memory");  // wave's out+hb stores acked
      if (lane == 0) astore(my_flag, (unsigned int)(t + 1));  // per-wave flag
    }
  }
}

// ---- host-side launch -----------------------------------------------------

extern "C" void kernel_launch(void* const* d_in, const int* in_sizes, int n_in,
                              void* d_out, int out_size, void* d_ws, size_t ws_size,
                              hipStream_t stream) {
  const float* x    = (const float*)d_in[0];   // 64*512*512
  const float* U    = (const float*)d_in[1];   // 512*4096
  const float* W    = (const float*)d_in[2];   // 1024*4096
  const float* bias = (const float*)d_in[3];   // 4096
  float* out = (float*)d_out;

  char* p = (char*)d_ws;
  unsigned short* xh = (unsigned short*)p; p += (size_t)64 * 512 * 512 * 2;   // 33.5 MB
  unsigned short* Wp = (unsigned short*)p; p += (size_t)4096 * 1024 * 2;      //  8.4 MB
  unsigned short* Up = (unsigned short*)p; p += (size_t)4096 * 512 * 2;       //  4.2 MB
  unsigned int*   hb = (unsigned int*)p;   p += (size_t)4 * 2 * 16 * 1024 * 2;// 256 KB
  unsigned int* flags = (unsigned int*)p;                                     //  4 KB

  hipMemsetAsync(flags, 0, 4 * 256 * sizeof(unsigned int), stream);
  cast_x_kernel<<<16384, 256, 0, stream>>>(x, xh);
  pack_W_kernel<<<2048, 256, 0, stream>>>(W, Wp);
  pack_U_kernel<<<1024, 256, 0, stream>>>(U, Up);
  // 16KB dynamic LDS pad: static 74.5KB -> 90.5KB so two WGs can't share a CU.
  lstm_rec_kernel<<<128, 512, 16384, stream>>>(xh, Wp, Up, bias, out, hb, flags);
}